// Round 25
// baseline (714.308 us; speedup 1.0000x reference)
//
#include <hip/hip_runtime.h>
#include <math.h>

#define NROWS 16384      // 32*512
#define DDIM  512
#define NE    4096
#define NZ    (NROWS * DDIM)
#define MAXC  64             // per-row kept-candidate cap (expected ~2)
#define MARGIN 2e-3f         // >= bound 2E + bucket + bf16 rounds ~ 1.4e-3

typedef __attribute__((ext_vector_type(8))) short bf16x8;
typedef __attribute__((ext_vector_type(4))) float f32x4;

__device__ __forceinline__ float sqr_rn(float x) { return __fmul_rn(x, x); }
__device__ __forceinline__ ushort f2bf(float f) {   // RNE f32->bf16
    const unsigned u = __float_as_uint(f);
    return (ushort)((u + 0x7fffu + ((u >> 16) & 1u)) >> 16);
}
__device__ __forceinline__ unsigned pack2(float a, float b) {
    return (unsigned)f2bf(a) | ((unsigned)f2bf(b) << 16);
}

// ---------------- kernel 1: fused prep (Z: numpy-exact znorm + bf16; E: bnorm + bf16) --
__global__ void k_prep(const float* __restrict__ z, const float* __restrict__ emb,
                       ushort* __restrict__ zh, ushort* __restrict__ eh,
                       float* __restrict__ znorm, float* __restrict__ bnorm,
                       unsigned* __restrict__ counts, unsigned* __restrict__ done) {
    if (blockIdx.x == 0 && threadIdx.x == 0) *done = 0u;
    if (blockIdx.x < 1024) {            // ---- E role: 4096 codes x 1 wave
        const int lane = threadIdx.x & 63;
        const int c = (int)((blockIdx.x * 256 + threadIdx.x) >> 6);
        const float4* p = (const float4*)(emb + (size_t)c * DDIM);
        const float4 v0 = p[lane * 2], v1 = p[lane * 2 + 1];
        uint4 w; w.x = pack2(v0.x, v0.y); w.y = pack2(v0.z, v0.w);
        w.z = pack2(v1.x, v1.y); w.w = pack2(v1.z, v1.w);
        *(uint4*)(eh + (size_t)c * DDIM + lane * 8) = w;
        float s = v0.x*v0.x + v0.y*v0.y + v0.z*v0.z + v0.w*v0.w
                + v1.x*v1.x + v1.y*v1.y + v1.z*v1.z + v1.w*v1.w;
        #pragma unroll
        for (int m = 32; m; m >>= 1) s += __shfl_xor(s, m);
        if (lane == 0) { bnorm[c] = s; counts[c] = 0u; }
    } else {                            // ---- Z role: numpy-exact pairwise znorm
        const int t = (int)((blockIdx.x - 1024) * 256 + threadIdx.x);   // 0..65535
        const int row = t >> 2, blk = t & 3;
        const float4* p = (const float4*)(z + (size_t)row * DDIM + blk * 128);
        ushort* zo = zh + (size_t)row * DDIM + blk * 128;
        float4 v0 = p[0], v1 = p[1];
        {
            uint4 w; w.x = pack2(v0.x, v0.y); w.y = pack2(v0.z, v0.w);
            w.z = pack2(v1.x, v1.y); w.w = pack2(v1.z, v1.w);
            *(uint4*)zo = w;
        }
        float r[8];
        r[0] = sqr_rn(v0.x); r[1] = sqr_rn(v0.y); r[2] = sqr_rn(v0.z); r[3] = sqr_rn(v0.w);
        r[4] = sqr_rn(v1.x); r[5] = sqr_rn(v1.y); r[6] = sqr_rn(v1.z); r[7] = sqr_rn(v1.w);
        #pragma unroll
        for (int i = 1; i < 16; ++i) {
            v0 = p[2 * i]; v1 = p[2 * i + 1];
            uint4 w; w.x = pack2(v0.x, v0.y); w.y = pack2(v0.z, v0.w);
            w.z = pack2(v1.x, v1.y); w.w = pack2(v1.z, v1.w);
            *(uint4*)(zo + i * 8) = w;
            r[0] = __fadd_rn(r[0], sqr_rn(v0.x)); r[1] = __fadd_rn(r[1], sqr_rn(v0.y));
            r[2] = __fadd_rn(r[2], sqr_rn(v0.z)); r[3] = __fadd_rn(r[3], sqr_rn(v0.w));
            r[4] = __fadd_rn(r[4], sqr_rn(v1.x)); r[5] = __fadd_rn(r[5], sqr_rn(v1.y));
            r[6] = __fadd_rn(r[6], sqr_rn(v1.z)); r[7] = __fadd_rn(r[7], sqr_rn(v1.w));
        }
        const float B = __fadd_rn(__fadd_rn(__fadd_rn(r[0], r[1]), __fadd_rn(r[2], r[3])),
                                  __fadd_rn(__fadd_rn(r[4], r[5]), __fadd_rn(r[6], r[7])));
        const float s01 = __fadd_rn(B, __shfl_xor(B, 1));     // in-wave quad reduce
        const float zn  = __fadd_rn(s01, __shfl_xor(s01, 2)); // ((B0+B1)+(B2+B3))
        if (blk == 0) znorm[row] = zn;
    }
}

// ---------------- kernel 2: bf16 MFMA GEMM (R20-verified: dbuf + early-issue) ----------
// grid (128, 32), block 256 = 4 waves (2x2 of 64x64). Tile 128x128, BK=32, 32KB LDS.
// Best-of-session core (148us, MfmaUtil 19.5, 0 conflicts). Double-buffered
// fragment-native LDS -> ONE barrier per K-step; tile-t+1 global loads issued before
// the MFMA block so L2 latency hides under MFMA. Fragment contents and MFMA
// accumulation order byte-identical to all passing rounds -> absmax 0 preserved.
// Epilogue straight-line (R18 lesson): packed uint2 sbuf stores + branch-free blkmin.
__global__ __launch_bounds__(256) void k_mfma(const ushort* __restrict__ zh,
                                              const ushort* __restrict__ eh,
                                              const float* __restrict__ bnorm,
                                              ushort* __restrict__ sbuf,
                                              float* __restrict__ rowblkmin) {
    __shared__ ushort Af[2][8 * 512];   // 2 x 8KB
    __shared__ ushort Bf[2][8 * 512];
    const int tid = threadIdx.x;
    const int lane = tid & 63;
    const int w = tid >> 6;
    const int wrow = (w >> 1) * 64, wcol = (w & 1) * 64;
    const int rbase = blockIdx.x * 128, cbase = blockIdx.y * 128;
    const int sr = tid >> 1, sh = tid & 1;            // staging: row 0..127, k-half 0..1
    const int g  = sr >> 4, r15 = sr & 15;            // staging chunk, row-in-chunk
    const int r16 = lane & 15, g4 = (lane >> 4) * 4;  // frag row/col, k-subgroup
    const int soff = g * 512 + r15 * 8 + sh * 4;      // LDS staging offset (ushorts)

    const ushort* ga = zh + (size_t)(rbase + sr) * DDIM + sh * 16;   // k=0 base
    const ushort* gb = eh + (size_t)(cbase + sr) * DDIM + sh * 16;

    f32x4 acc[4][4];
    #pragma unroll
    for (int i = 0; i < 4; ++i)
        #pragma unroll
        for (int j = 0; j < 4; ++j) acc[i][j] = (f32x4){0.f, 0.f, 0.f, 0.f};

    // prologue: load tile 0 and stage into buf 0
    {
        const uint4 qa0 = *(const uint4*)ga;
        const uint4 qa1 = *(const uint4*)(ga + 8);
        const uint4 qb0 = *(const uint4*)gb;
        const uint4 qb1 = *(const uint4*)(gb + 8);
        ushort* pa = &Af[0][soff];
        *(uint2*)(pa +   0) = make_uint2(qa0.x, qa0.y);
        *(uint2*)(pa + 128) = make_uint2(qa0.z, qa0.w);
        *(uint2*)(pa + 256) = make_uint2(qa1.x, qa1.y);
        *(uint2*)(pa + 384) = make_uint2(qa1.z, qa1.w);
        ushort* pb = &Bf[0][soff];
        *(uint2*)(pb +   0) = make_uint2(qb0.x, qb0.y);
        *(uint2*)(pb + 128) = make_uint2(qb0.z, qb0.w);
        *(uint2*)(pb + 256) = make_uint2(qb1.x, qb1.y);
        *(uint2*)(pb + 384) = make_uint2(qb1.z, qb1.w);
    }
    __syncthreads();

    for (int kb = 0; kb < DDIM; kb += 32) {
        const int cur = (kb >> 5) & 1;
        const bool more = (kb + 32 < DDIM);
        uint4 na0, na1, nb0, nb1;
        if (more) {     // issue next-tile loads FIRST: latency overlaps MFMA below
            na0 = *(const uint4*)(ga + kb + 32);
            na1 = *(const uint4*)(ga + kb + 40);
            nb0 = *(const uint4*)(gb + kb + 32);
            nb1 = *(const uint4*)(gb + kb + 40);
        }
        bf16x8 af[4], bf[4];
        #pragma unroll
        for (int f = 0; f < 4; ++f) {
            af[f] = *(const bf16x8*)&Af[cur][((wrow >> 4) + f) * 512 + lane * 8];
            bf[f] = *(const bf16x8*)&Bf[cur][((wcol >> 4) + f) * 512 + lane * 8];
        }
        #pragma unroll
        for (int fi = 0; fi < 4; ++fi)
            #pragma unroll
            for (int fj = 0; fj < 4; ++fj)
                acc[fi][fj] = __builtin_amdgcn_mfma_f32_16x16x32_bf16(
                    af[fi], bf[fj], acc[fi][fj], 0, 0, 0);
        if (more) {     // stage tile t+1 (readers finished before the prev barrier)
            ushort* pa = &Af[cur ^ 1][soff];
            *(uint2*)(pa +   0) = make_uint2(na0.x, na0.y);
            *(uint2*)(pa + 128) = make_uint2(na0.z, na0.w);
            *(uint2*)(pa + 256) = make_uint2(na1.x, na1.y);
            *(uint2*)(pa + 384) = make_uint2(na1.z, na1.w);
            ushort* pb = &Bf[cur ^ 1][soff];
            *(uint2*)(pb +   0) = make_uint2(nb0.x, nb0.y);
            *(uint2*)(pb + 128) = make_uint2(nb0.z, nb0.w);
            *(uint2*)(pb + 256) = make_uint2(nb1.x, nb1.y);
            *(uint2*)(pb + 384) = make_uint2(nb1.z, nb1.w);
            __syncthreads();
        }
    }

    // C/D layout: value (fi,fj,r) -> row = wrow+fi*16+g4+r, col = wcol+fj*16+r16
    float bn[4];
    #pragma unroll
    for (int fj = 0; fj < 4; ++fj) bn[fj] = bnorm[cbase + wcol + fj * 16 + r16];

    #pragma unroll
    for (int fi = 0; fi < 4; ++fi) {
        #pragma unroll
        for (int r = 0; r < 4; ++r) {
            const int row = rbase + wrow + fi * 16 + g4 + r;
            float s[4];
            #pragma unroll
            for (int fj = 0; fj < 4; ++fj) s[fj] = fmaf(-2.f, acc[fi][fj][r], bn[fj]);
            uint2* sp = (uint2*)(sbuf + (size_t)row * NE + cbase + wcol);
            sp[r16] = make_uint2(pack2(s[0], s[1]), pack2(s[2], s[3]));
            float m = fminf(fminf(s[0], s[1]), fminf(s[2], s[3]));
            #pragma unroll
            for (int x = 1; x < 16; x <<= 1) m = fminf(m, __shfl_xor(m, x));  // 16-lane grp
            if (r16 == 0)
                rowblkmin[(size_t)row * 64 + blockIdx.y * 2 + (w & 1)] = m;
        }
    }
}

// ---------------- exact numpy chain: sequential ascending-k FMA + exact bucketing ------
__device__ __forceinline__ unsigned long long exact_key(const float4* __restrict__ zp4,
                                                        const float* __restrict__ emb,
                                                        const float* __restrict__ bnorm,
                                                        float zn, int c) {
    const float4* ep4 = (const float4*)(emb + (size_t)c * DDIM);
    float acc = 0.f;
    #pragma unroll 8
    for (int q = 0; q < DDIM / 4; ++q) {
        const float4 zv = zp4[q];
        const float4 ev = ep4[q];
        acc = fmaf(zv.x, ev.x, acc);
        acc = fmaf(zv.y, ev.y, acc);
        acc = fmaf(zv.z, ev.z, acc);
        acc = fmaf(zv.w, ev.w, acc);
    }
    const float s = __fsub_rn(__fadd_rn(zn, bnorm[c]), __fmul_rn(2.f, acc));
    return ((unsigned long long)__float_as_uint(s) << 32) | (unsigned)c;
}

// ---------------- kernel 3: guided pick + exact resolve + gather + STE + finalize ------
// one wave per row; candidates only in per-wave LDS; writes out. Last block to finish
// (device-scope done-counter, release via __threadfence before atomicAdd, acquire via
// fence after) runs the loss/perplexity finalize with all 256 threads — deterministic:
// the finalize reads fully-written counts/d2buf regardless of which block is last.
__global__ void k_pg(const ushort* __restrict__ sbuf, const float* __restrict__ rowblkmin,
                     const float* __restrict__ z, const float* __restrict__ emb,
                     const float* __restrict__ znorm, const float* __restrict__ bnorm,
                     float* __restrict__ out, unsigned* __restrict__ counts,
                     float* __restrict__ d2buf, unsigned* __restrict__ done) {
    __shared__ int candL[4][MAXC];
    __shared__ unsigned cntL[4];
    const int lane = threadIdx.x & 63;
    const int w = threadIdx.x >> 6;
    const int row = blockIdx.x * 4 + w;
    if (threadIdx.x < 4) cntL[threadIdx.x] = 0u;
    __syncthreads();

    const float bm = rowblkmin[(size_t)row * 64 + lane];
    float gmin = bm;
    #pragma unroll
    for (int m = 32; m; m >>= 1) gmin = fminf(gmin, __shfl_xor(gmin, m));
    const float thr = gmin + MARGIN;
    unsigned long long bmask = __ballot(bm <= thr);   // expected ~1.3 blocks
    while (bmask) {
        const int b = __builtin_ctzll(bmask); bmask &= bmask - 1;
        const float val = __uint_as_float(
            (unsigned)sbuf[(size_t)row * NE + b * 64 + lane] << 16);
        if (val <= thr) {
            const unsigned slot = atomicAdd(&cntL[w], 1u);
            if (slot < MAXC)
                candL[w][slot] = b * 64 + (lane & 3) * 16 + (lane >> 2);
        }
    }
    __syncthreads();

    const int cnt = (int)cntL[w];
    int id;
    if (cnt == 1) {
        id = candL[w][0] & (NE - 1);
    } else {
        const float zn = znorm[row];
        const float4* zp4 = (const float4*)(z + (size_t)row * DDIM);
        unsigned long long best = ~0ULL;
        if (cnt >= 2 && cnt <= MAXC) {
            if (lane < cnt)
                best = exact_key(zp4, emb, bnorm, zn, candL[w][lane] & (NE - 1));
        } else {             // cnt==0 (impossible) or overflow: exact scan of all codes
            for (int c = lane; c < NE; c += 64) {
                const unsigned long long k = exact_key(zp4, emb, bnorm, zn, c);
                if (k < best) best = k;
            }
        }
        #pragma unroll
        for (int m = 32; m; m >>= 1) {
            const unsigned long long ov = __shfl_xor(best, m);
            if (ov < best) best = ov;
        }
        id = (int)(__shfl(best, 0) & (unsigned long long)(NE - 1));
    }

    const float* zp = z + (size_t)row * DDIM;
    const float* ep = emb + (size_t)id * DDIM;
    float* op = out + 1 + (size_t)row * DDIM;
    float d2 = 0.f;
    #pragma unroll
    for (int m = 0; m < 8; ++m) {
        const int k = m * 64 + lane;
        const float e = ep[k];
        const float zv = zp[k];
        const float t = e - zv;          // two-step rounding matches reference STE
        op[k] = zv + t;
        d2 = fmaf(t, t, d2);
    }
    #pragma unroll
    for (int m = 32; m; m >>= 1) d2 += __shfl_xor(d2, m);
    if (lane == 0) {
        atomicAdd(&counts[id], 1u);
        d2buf[row] = d2;
        out[1 + (size_t)NZ + row] = (float)id;
    }

    // ---- last-block finalize (replaces the k_final launch) ----
    __threadfence();                      // release this block's writes
    __shared__ unsigned lastf;
    if (threadIdx.x == 0) {
        const unsigned t = atomicAdd(done, 1u);
        lastf = (t == gridDim.x - 1) ? 1u : 0u;
    }
    __syncthreads();
    if (lastf) {
        __threadfence();                  // acquire all blocks' writes
        __shared__ double sh[256];
        __shared__ float  shf[256];
        const int tid = threadIdx.x;
        double ent = 0.0;
        for (int i = tid; i < NE; i += 256) {
            const double p = (double)counts[i] / (double)NROWS;
            ent += p * log(p + 1e-10);
        }
        float sse = 0.f;
        for (int i = tid; i < NROWS; i += 256) sse += d2buf[i];
        sh[tid] = ent; shf[tid] = sse;
        __syncthreads();
        for (int s = 128; s; s >>= 1) {
            if (tid < s) { sh[tid] += sh[tid + s]; shf[tid] += shf[tid + s]; }
            __syncthreads();
        }
        if (tid == 0) {
            out[0] = 1.25f * (shf[0] / (float)NZ);
            out[1 + (size_t)NZ + NROWS] = (float)exp(-sh[0]);
        }
    }
}

extern "C" void kernel_launch(void* const* d_in, const int* in_sizes, int n_in,
                              void* d_out, int out_size, void* d_ws, size_t ws_size,
                              hipStream_t stream) {
    const float* z   = (const float*)d_in[0];
    const float* emb = (const float*)d_in[1];
    float* out = (float*)d_out;
    char* ws = (char*)d_ws;

    // zh/eh live inside out[1..NZ]: written by k_prep, read by k_mfma, and only
    // k_pg (strictly later in stream order) writes out -> no overlap anywhere.
    ushort* zh = (ushort*)(out + 4);                       // 16 MB
    ushort* eh = (ushort*)(out + 4 + 4194304);             //  4 MB

    size_t off = 0;
    float*    bnorm  = (float*)(ws + off); off += (size_t)NE * 4;          // 16KB
    unsigned* counts = (unsigned*)(ws + off); off += (size_t)NE * 4;       // 16KB
    float*    d2buf  = (float*)(ws + off); off += (size_t)NROWS * 4;       // 64KB
    float*    znorm  = (float*)(ws + off); off += (size_t)NROWS * 4;       // 64KB
    unsigned* done   = (unsigned*)(ws + off); off += 256;                  // 256B (aligned)
    ushort*   sbuf   = (ushort*)(ws + off); off += (size_t)NROWS * NE * 2; // 128MB
    float*    rowblkmin = (float*)(ws + off); off += (size_t)NROWS * 64 * 4; // 4MB
    // total ~132.5MB == proven footprint

    k_prep<<<1280, 256, 0, stream>>>(z, emb, zh, eh, znorm, bnorm, counts, done);
    k_mfma<<<dim3(NROWS / 128, NE / 128), 256, 0, stream>>>(zh, eh, bnorm, sbuf, rowblkmin);
    k_pg<<<NROWS / 4, 256, 0, stream>>>(sbuf, rowblkmin, z, emb, znorm, bnorm, out, counts, d2buf, done);
}

// Round 26
// 274.925 us; speedup vs baseline: 2.5982x; 2.5982x over previous
//
#include <hip/hip_runtime.h>
#include <math.h>

#define NROWS 16384      // 32*512
#define DDIM  512
#define NE    4096
#define NZ    (NROWS * DDIM)
#define MAXC  64             // per-row kept-candidate cap (expected ~2)
#define MARGIN 2e-3f         // >= bound 2E + bucket + bf16 rounds ~ 1.4e-3

typedef __attribute__((ext_vector_type(8))) short bf16x8;
typedef __attribute__((ext_vector_type(4))) float f32x4;

__device__ __forceinline__ float sqr_rn(float x) { return __fmul_rn(x, x); }
__device__ __forceinline__ ushort f2bf(float f) {   // RNE f32->bf16
    const unsigned u = __float_as_uint(f);
    return (ushort)((u + 0x7fffu + ((u >> 16) & 1u)) >> 16);
}
__device__ __forceinline__ unsigned pack2(float a, float b) {
    return (unsigned)f2bf(a) | ((unsigned)f2bf(b) << 16);
}

// ---------------- kernel 1: fused prep (Z: numpy-exact znorm + bf16; E: bnorm + bf16) --
__global__ void k_prep(const float* __restrict__ z, const float* __restrict__ emb,
                       ushort* __restrict__ zh, ushort* __restrict__ eh,
                       float* __restrict__ znorm, float* __restrict__ bnorm,
                       unsigned* __restrict__ counts) {
    if (blockIdx.x < 1024) {            // ---- E role: 4096 codes x 1 wave
        const int lane = threadIdx.x & 63;
        const int c = (int)((blockIdx.x * 256 + threadIdx.x) >> 6);
        const float4* p = (const float4*)(emb + (size_t)c * DDIM);
        const float4 v0 = p[lane * 2], v1 = p[lane * 2 + 1];
        uint4 w; w.x = pack2(v0.x, v0.y); w.y = pack2(v0.z, v0.w);
        w.z = pack2(v1.x, v1.y); w.w = pack2(v1.z, v1.w);
        *(uint4*)(eh + (size_t)c * DDIM + lane * 8) = w;
        float s = v0.x*v0.x + v0.y*v0.y + v0.z*v0.z + v0.w*v0.w
                + v1.x*v1.x + v1.y*v1.y + v1.z*v1.z + v1.w*v1.w;
        #pragma unroll
        for (int m = 32; m; m >>= 1) s += __shfl_xor(s, m);
        if (lane == 0) { bnorm[c] = s; counts[c] = 0u; }
    } else {                            // ---- Z role: numpy-exact pairwise znorm
        const int t = (int)((blockIdx.x - 1024) * 256 + threadIdx.x);   // 0..65535
        const int row = t >> 2, blk = t & 3;
        const float4* p = (const float4*)(z + (size_t)row * DDIM + blk * 128);
        ushort* zo = zh + (size_t)row * DDIM + blk * 128;
        float4 v0 = p[0], v1 = p[1];
        {
            uint4 w; w.x = pack2(v0.x, v0.y); w.y = pack2(v0.z, v0.w);
            w.z = pack2(v1.x, v1.y); w.w = pack2(v1.z, v1.w);
            *(uint4*)zo = w;
        }
        float r[8];
        r[0] = sqr_rn(v0.x); r[1] = sqr_rn(v0.y); r[2] = sqr_rn(v0.z); r[3] = sqr_rn(v0.w);
        r[4] = sqr_rn(v1.x); r[5] = sqr_rn(v1.y); r[6] = sqr_rn(v1.z); r[7] = sqr_rn(v1.w);
        #pragma unroll
        for (int i = 1; i < 16; ++i) {
            v0 = p[2 * i]; v1 = p[2 * i + 1];
            uint4 w; w.x = pack2(v0.x, v0.y); w.y = pack2(v0.z, v0.w);
            w.z = pack2(v1.x, v1.y); w.w = pack2(v1.z, v1.w);
            *(uint4*)(zo + i * 8) = w;
            r[0] = __fadd_rn(r[0], sqr_rn(v0.x)); r[1] = __fadd_rn(r[1], sqr_rn(v0.y));
            r[2] = __fadd_rn(r[2], sqr_rn(v0.z)); r[3] = __fadd_rn(r[3], sqr_rn(v0.w));
            r[4] = __fadd_rn(r[4], sqr_rn(v1.x)); r[5] = __fadd_rn(r[5], sqr_rn(v1.y));
            r[6] = __fadd_rn(r[6], sqr_rn(v1.z)); r[7] = __fadd_rn(r[7], sqr_rn(v1.w));
        }
        const float B = __fadd_rn(__fadd_rn(__fadd_rn(r[0], r[1]), __fadd_rn(r[2], r[3])),
                                  __fadd_rn(__fadd_rn(r[4], r[5]), __fadd_rn(r[6], r[7])));
        const float s01 = __fadd_rn(B, __shfl_xor(B, 1));     // in-wave quad reduce
        const float zn  = __fadd_rn(s01, __shfl_xor(s01, 2)); // ((B0+B1)+(B2+B3))
        if (blk == 0) znorm[row] = zn;
    }
}

// ---------------- kernel 2: bf16 MFMA GEMM (R20-verified: dbuf + early-issue) ----------
// grid (128, 32), block 256 = 4 waves (2x2 of 64x64). Tile 128x128, BK=32, 32KB LDS.
// Best-of-session core (148us, MfmaUtil 19.5, 0 conflicts). Double-buffered
// fragment-native LDS -> ONE barrier per K-step; tile-t+1 global loads issued before
// the MFMA block so L2 latency hides under MFMA. Fragment contents and MFMA
// accumulation order byte-identical to all passing rounds -> absmax 0 preserved.
// Epilogue straight-line (R18 lesson): packed uint2 sbuf stores + branch-free blkmin.
__global__ __launch_bounds__(256) void k_mfma(const ushort* __restrict__ zh,
                                              const ushort* __restrict__ eh,
                                              const float* __restrict__ bnorm,
                                              ushort* __restrict__ sbuf,
                                              float* __restrict__ rowblkmin) {
    __shared__ ushort Af[2][8 * 512];   // 2 x 8KB
    __shared__ ushort Bf[2][8 * 512];
    const int tid = threadIdx.x;
    const int lane = tid & 63;
    const int w = tid >> 6;
    const int wrow = (w >> 1) * 64, wcol = (w & 1) * 64;
    const int rbase = blockIdx.x * 128, cbase = blockIdx.y * 128;
    const int sr = tid >> 1, sh = tid & 1;            // staging: row 0..127, k-half 0..1
    const int g  = sr >> 4, r15 = sr & 15;            // staging chunk, row-in-chunk
    const int r16 = lane & 15, g4 = (lane >> 4) * 4;  // frag row/col, k-subgroup
    const int soff = g * 512 + r15 * 8 + sh * 4;      // LDS staging offset (ushorts)

    const ushort* ga = zh + (size_t)(rbase + sr) * DDIM + sh * 16;   // k=0 base
    const ushort* gb = eh + (size_t)(cbase + sr) * DDIM + sh * 16;

    f32x4 acc[4][4];
    #pragma unroll
    for (int i = 0; i < 4; ++i)
        #pragma unroll
        for (int j = 0; j < 4; ++j) acc[i][j] = (f32x4){0.f, 0.f, 0.f, 0.f};

    // prologue: load tile 0 and stage into buf 0
    {
        const uint4 qa0 = *(const uint4*)ga;
        const uint4 qa1 = *(const uint4*)(ga + 8);
        const uint4 qb0 = *(const uint4*)gb;
        const uint4 qb1 = *(const uint4*)(gb + 8);
        ushort* pa = &Af[0][soff];
        *(uint2*)(pa +   0) = make_uint2(qa0.x, qa0.y);
        *(uint2*)(pa + 128) = make_uint2(qa0.z, qa0.w);
        *(uint2*)(pa + 256) = make_uint2(qa1.x, qa1.y);
        *(uint2*)(pa + 384) = make_uint2(qa1.z, qa1.w);
        ushort* pb = &Bf[0][soff];
        *(uint2*)(pb +   0) = make_uint2(qb0.x, qb0.y);
        *(uint2*)(pb + 128) = make_uint2(qb0.z, qb0.w);
        *(uint2*)(pb + 256) = make_uint2(qb1.x, qb1.y);
        *(uint2*)(pb + 384) = make_uint2(qb1.z, qb1.w);
    }
    __syncthreads();

    for (int kb = 0; kb < DDIM; kb += 32) {
        const int cur = (kb >> 5) & 1;
        const bool more = (kb + 32 < DDIM);
        uint4 na0, na1, nb0, nb1;
        if (more) {     // issue next-tile loads FIRST: latency overlaps MFMA below
            na0 = *(const uint4*)(ga + kb + 32);
            na1 = *(const uint4*)(ga + kb + 40);
            nb0 = *(const uint4*)(gb + kb + 32);
            nb1 = *(const uint4*)(gb + kb + 40);
        }
        bf16x8 af[4], bf[4];
        #pragma unroll
        for (int f = 0; f < 4; ++f) {
            af[f] = *(const bf16x8*)&Af[cur][((wrow >> 4) + f) * 512 + lane * 8];
            bf[f] = *(const bf16x8*)&Bf[cur][((wcol >> 4) + f) * 512 + lane * 8];
        }
        #pragma unroll
        for (int fi = 0; fi < 4; ++fi)
            #pragma unroll
            for (int fj = 0; fj < 4; ++fj)
                acc[fi][fj] = __builtin_amdgcn_mfma_f32_16x16x32_bf16(
                    af[fi], bf[fj], acc[fi][fj], 0, 0, 0);
        if (more) {     // stage tile t+1 (readers finished before the prev barrier)
            ushort* pa = &Af[cur ^ 1][soff];
            *(uint2*)(pa +   0) = make_uint2(na0.x, na0.y);
            *(uint2*)(pa + 128) = make_uint2(na0.z, na0.w);
            *(uint2*)(pa + 256) = make_uint2(na1.x, na1.y);
            *(uint2*)(pa + 384) = make_uint2(na1.z, na1.w);
            ushort* pb = &Bf[cur ^ 1][soff];
            *(uint2*)(pb +   0) = make_uint2(nb0.x, nb0.y);
            *(uint2*)(pb + 128) = make_uint2(nb0.z, nb0.w);
            *(uint2*)(pb + 256) = make_uint2(nb1.x, nb1.y);
            *(uint2*)(pb + 384) = make_uint2(nb1.z, nb1.w);
            __syncthreads();
        }
    }

    // C/D layout: value (fi,fj,r) -> row = wrow+fi*16+g4+r, col = wcol+fj*16+r16
    float bn[4];
    #pragma unroll
    for (int fj = 0; fj < 4; ++fj) bn[fj] = bnorm[cbase + wcol + fj * 16 + r16];

    #pragma unroll
    for (int fi = 0; fi < 4; ++fi) {
        #pragma unroll
        for (int r = 0; r < 4; ++r) {
            const int row = rbase + wrow + fi * 16 + g4 + r;
            float s[4];
            #pragma unroll
            for (int fj = 0; fj < 4; ++fj) s[fj] = fmaf(-2.f, acc[fi][fj][r], bn[fj]);
            uint2* sp = (uint2*)(sbuf + (size_t)row * NE + cbase + wcol);
            sp[r16] = make_uint2(pack2(s[0], s[1]), pack2(s[2], s[3]));
            float m = fminf(fminf(s[0], s[1]), fminf(s[2], s[3]));
            #pragma unroll
            for (int x = 1; x < 16; x <<= 1) m = fminf(m, __shfl_xor(m, x));  // 16-lane grp
            if (r16 == 0)
                rowblkmin[(size_t)row * 64 + blockIdx.y * 2 + (w & 1)] = m;
        }
    }
}

// ---------------- exact numpy chain: sequential ascending-k FMA + exact bucketing ------
__device__ __forceinline__ unsigned long long exact_key(const float4* __restrict__ zp4,
                                                        const float* __restrict__ emb,
                                                        const float* __restrict__ bnorm,
                                                        float zn, int c) {
    const float4* ep4 = (const float4*)(emb + (size_t)c * DDIM);
    float acc = 0.f;
    #pragma unroll 8
    for (int q = 0; q < DDIM / 4; ++q) {
        const float4 zv = zp4[q];
        const float4 ev = ep4[q];
        acc = fmaf(zv.x, ev.x, acc);
        acc = fmaf(zv.y, ev.y, acc);
        acc = fmaf(zv.z, ev.z, acc);
        acc = fmaf(zv.w, ev.w, acc);
    }
    const float s = __fsub_rn(__fadd_rn(zn, bnorm[c]), __fmul_rn(2.f, acc));
    return ((unsigned long long)__float_as_uint(s) << 32) | (unsigned)c;
}

// ---------------- kernel 3: guided pick + exact resolve + gather + STE ----------------
// one wave per row; reads rowblkmin (4MB) + only flagged sbuf segments (~1.3 x 128B/row);
// candidates live only in per-wave LDS (no cross-block races); writes out.
// sbuf in-64-block permutation: col = b*64 + (i&3)*16 + (i>>2).
__global__ void k_pg(const ushort* __restrict__ sbuf, const float* __restrict__ rowblkmin,
                     const float* __restrict__ z, const float* __restrict__ emb,
                     const float* __restrict__ znorm, const float* __restrict__ bnorm,
                     float* __restrict__ out, unsigned* __restrict__ counts,
                     float* __restrict__ d2buf) {
    __shared__ int candL[4][MAXC];
    __shared__ unsigned cntL[4];
    const int lane = threadIdx.x & 63;
    const int w = threadIdx.x >> 6;
    const int row = blockIdx.x * 4 + w;
    if (threadIdx.x < 4) cntL[threadIdx.x] = 0u;
    __syncthreads();

    const float bm = rowblkmin[(size_t)row * 64 + lane];
    float gmin = bm;
    #pragma unroll
    for (int m = 32; m; m >>= 1) gmin = fminf(gmin, __shfl_xor(gmin, m));
    const float thr = gmin + MARGIN;
    unsigned long long bmask = __ballot(bm <= thr);   // expected ~1.3 blocks
    while (bmask) {
        const int b = __builtin_ctzll(bmask); bmask &= bmask - 1;
        const float val = __uint_as_float(
            (unsigned)sbuf[(size_t)row * NE + b * 64 + lane] << 16);
        if (val <= thr) {
            const unsigned slot = atomicAdd(&cntL[w], 1u);
            if (slot < MAXC)
                candL[w][slot] = b * 64 + (lane & 3) * 16 + (lane >> 2);
        }
    }
    __syncthreads();

    const int cnt = (int)cntL[w];
    int id;
    if (cnt == 1) {
        id = candL[w][0] & (NE - 1);
    } else {
        const float zn = znorm[row];
        const float4* zp4 = (const float4*)(z + (size_t)row * DDIM);
        unsigned long long best = ~0ULL;
        if (cnt >= 2 && cnt <= MAXC) {
            if (lane < cnt)
                best = exact_key(zp4, emb, bnorm, zn, candL[w][lane] & (NE - 1));
        } else {             // cnt==0 (impossible) or overflow: exact scan of all codes
            for (int c = lane; c < NE; c += 64) {
                const unsigned long long k = exact_key(zp4, emb, bnorm, zn, c);
                if (k < best) best = k;
            }
        }
        #pragma unroll
        for (int m = 32; m; m >>= 1) {
            const unsigned long long ov = __shfl_xor(best, m);
            if (ov < best) best = ov;
        }
        id = (int)(__shfl(best, 0) & (unsigned long long)(NE - 1));
    }

    const float* zp = z + (size_t)row * DDIM;
    const float* ep = emb + (size_t)id * DDIM;
    float* op = out + 1 + (size_t)row * DDIM;
    float d2 = 0.f;
    #pragma unroll
    for (int m = 0; m < 8; ++m) {
        const int k = m * 64 + lane;
        const float e = ep[k];
        const float zv = zp[k];
        const float t = e - zv;          // two-step rounding matches reference STE
        op[k] = zv + t;
        d2 = fmaf(t, t, d2);
    }
    #pragma unroll
    for (int m = 32; m; m >>= 1) d2 += __shfl_xor(d2, m);
    if (lane == 0) {
        atomicAdd(&counts[id], 1u);
        d2buf[row] = d2;
        out[1 + (size_t)NZ + row] = (float)id;
    }
}

// ---------------- kernel 4: finalize loss + perplexity ----------------
__global__ void k_final(const float* __restrict__ d2buf, const unsigned* __restrict__ counts,
                        float* __restrict__ out) {
    __shared__ double sh[256];
    __shared__ float  shf[256];
    const int tid = threadIdx.x;
    double ent = 0.0;
    for (int i = tid; i < NE; i += 256) {
        const double p = (double)counts[i] / (double)NROWS;
        ent += p * log(p + 1e-10);
    }
    float sse = 0.f;
    for (int i = tid; i < NROWS; i += 256) sse += d2buf[i];
    sh[tid] = ent; shf[tid] = sse;
    __syncthreads();
    for (int s = 128; s; s >>= 1) {
        if (tid < s) { sh[tid] += sh[tid + s]; shf[tid] += shf[tid + s]; }
        __syncthreads();
    }
    if (tid == 0) {
        out[0] = 1.25f * (shf[0] / (float)NZ);
        out[1 + (size_t)NZ + NROWS] = (float)exp(-sh[0]);
    }
}

extern "C" void kernel_launch(void* const* d_in, const int* in_sizes, int n_in,
                              void* d_out, int out_size, void* d_ws, size_t ws_size,
                              hipStream_t stream) {
    const float* z   = (const float*)d_in[0];
    const float* emb = (const float*)d_in[1];
    float* out = (float*)d_out;
    char* ws = (char*)d_ws;

    // zh/eh live inside out[1..NZ]: written by k_prep, read by k_mfma, and only
    // k_pg (strictly later in stream order) writes out -> no overlap anywhere.
    ushort* zh = (ushort*)(out + 4);                       // 16 MB
    ushort* eh = (ushort*)(out + 4 + 4194304);             //  4 MB

    size_t off = 0;
    float*    bnorm  = (float*)(ws + off); off += (size_t)NE * 4;          // 16KB
    unsigned* counts = (unsigned*)(ws + off); off += (size_t)NE * 4;       // 16KB
    float*    d2buf  = (float*)(ws + off); off += (size_t)NROWS * 4;       // 64KB
    float*    znorm  = (float*)(ws + off); off += (size_t)NROWS * 4;       // 64KB
    ushort*   sbuf   = (ushort*)(ws + off); off += (size_t)NROWS * NE * 2; // 128MB
    float*    rowblkmin = (float*)(ws + off); off += (size_t)NROWS * 64 * 4; // 4MB
    // total ~132.5MB == proven footprint

    k_prep<<<1280, 256, 0, stream>>>(z, emb, zh, eh, znorm, bnorm, counts);
    k_mfma<<<dim3(NROWS / 128, NE / 128), 256, 0, stream>>>(zh, eh, bnorm, sbuf, rowblkmin);
    k_pg<<<NROWS / 4, 256, 0, stream>>>(sbuf, rowblkmin, z, emb, znorm, bnorm, out, counts, d2buf);
    k_final<<<1, 256, 0, stream>>>(d2buf, counts, out);
}

// Round 27
// 269.934 us; speedup vs baseline: 2.6462x; 1.0185x over previous
//
#include <hip/hip_runtime.h>
#include <math.h>

#define NROWS 16384      // 32*512
#define DDIM  512
#define NE    4096
#define NZ    (NROWS * DDIM)
#define MAXC  64             // per-row kept-candidate cap (expected ~2)
#define MARGIN 2e-3f         // >= bound 2E + bucket + bf16 rounds ~ 1.4e-3

typedef __attribute__((ext_vector_type(8))) short bf16x8;
typedef __attribute__((ext_vector_type(4))) float f32x4;

__device__ __forceinline__ float sqr_rn(float x) { return __fmul_rn(x, x); }
__device__ __forceinline__ ushort f2bf(float f) {   // RNE f32->bf16
    const unsigned u = __float_as_uint(f);
    return (ushort)((u + 0x7fffu + ((u >> 16) & 1u)) >> 16);
}
__device__ __forceinline__ unsigned pack2(float a, float b) {
    return (unsigned)f2bf(a) | ((unsigned)f2bf(b) << 16);
}

// ---------------- kernel 1: fused prep (Z: numpy-exact znorm + bf16; E: bnorm + bf16) --
__global__ void k_prep(const float* __restrict__ z, const float* __restrict__ emb,
                       ushort* __restrict__ zh, ushort* __restrict__ eh,
                       float* __restrict__ znorm, float* __restrict__ bnorm,
                       unsigned* __restrict__ counts) {
    if (blockIdx.x < 1024) {            // ---- E role: 4096 codes x 1 wave
        const int lane = threadIdx.x & 63;
        const int c = (int)((blockIdx.x * 256 + threadIdx.x) >> 6);
        const float4* p = (const float4*)(emb + (size_t)c * DDIM);
        const float4 v0 = p[lane * 2], v1 = p[lane * 2 + 1];
        uint4 w; w.x = pack2(v0.x, v0.y); w.y = pack2(v0.z, v0.w);
        w.z = pack2(v1.x, v1.y); w.w = pack2(v1.z, v1.w);
        *(uint4*)(eh + (size_t)c * DDIM + lane * 8) = w;
        float s = v0.x*v0.x + v0.y*v0.y + v0.z*v0.z + v0.w*v0.w
                + v1.x*v1.x + v1.y*v1.y + v1.z*v1.z + v1.w*v1.w;
        #pragma unroll
        for (int m = 32; m; m >>= 1) s += __shfl_xor(s, m);
        if (lane == 0) { bnorm[c] = s; counts[c] = 0u; }
    } else {                            // ---- Z role: numpy-exact pairwise znorm
        const int t = (int)((blockIdx.x - 1024) * 256 + threadIdx.x);   // 0..65535
        const int row = t >> 2, blk = t & 3;
        const float4* p = (const float4*)(z + (size_t)row * DDIM + blk * 128);
        ushort* zo = zh + (size_t)row * DDIM + blk * 128;
        float4 v0 = p[0], v1 = p[1];
        {
            uint4 w; w.x = pack2(v0.x, v0.y); w.y = pack2(v0.z, v0.w);
            w.z = pack2(v1.x, v1.y); w.w = pack2(v1.z, v1.w);
            *(uint4*)zo = w;
        }
        float r[8];
        r[0] = sqr_rn(v0.x); r[1] = sqr_rn(v0.y); r[2] = sqr_rn(v0.z); r[3] = sqr_rn(v0.w);
        r[4] = sqr_rn(v1.x); r[5] = sqr_rn(v1.y); r[6] = sqr_rn(v1.z); r[7] = sqr_rn(v1.w);
        #pragma unroll
        for (int i = 1; i < 16; ++i) {
            v0 = p[2 * i]; v1 = p[2 * i + 1];
            uint4 w; w.x = pack2(v0.x, v0.y); w.y = pack2(v0.z, v0.w);
            w.z = pack2(v1.x, v1.y); w.w = pack2(v1.z, v1.w);
            *(uint4*)(zo + i * 8) = w;
            r[0] = __fadd_rn(r[0], sqr_rn(v0.x)); r[1] = __fadd_rn(r[1], sqr_rn(v0.y));
            r[2] = __fadd_rn(r[2], sqr_rn(v0.z)); r[3] = __fadd_rn(r[3], sqr_rn(v0.w));
            r[4] = __fadd_rn(r[4], sqr_rn(v1.x)); r[5] = __fadd_rn(r[5], sqr_rn(v1.y));
            r[6] = __fadd_rn(r[6], sqr_rn(v1.z)); r[7] = __fadd_rn(r[7], sqr_rn(v1.w));
        }
        const float B = __fadd_rn(__fadd_rn(__fadd_rn(r[0], r[1]), __fadd_rn(r[2], r[3])),
                                  __fadd_rn(__fadd_rn(r[4], r[5]), __fadd_rn(r[6], r[7])));
        const float s01 = __fadd_rn(B, __shfl_xor(B, 1));     // in-wave quad reduce
        const float zn  = __fadd_rn(s01, __shfl_xor(s01, 2)); // ((B0+B1)+(B2+B3))
        if (blk == 0) znorm[row] = zn;
    }
}

// ---------------- kernel 2: bf16 MFMA GEMM (R20 core + 2-deep load pipeline) -----------
// grid (128, 32), block 256 = 4 waves (2x2 of 64x64). Tile 128x128, BK=32, 32KB LDS.
// R26 diagnosis: latency-structure bound — stage(t+1)'s vmcnt wait lands on the barrier
// path because its loads (issued this iteration) have only the MFMA block (~320cy) to
// cover ~200-400cy L2 latency. 2-deep: issue loads for tile t+2 BEFORE the MFMA block,
// stage tile t+1 from regs held since last iteration -> each load has ~1.5 iterations
// (~900cy) to land. K-loop fully unrolled: buffer index & tails static, reg rotation
// via SSA (no dynamic indexing). Fragment contents and per-(fi,fj) MFMA chain are
// byte-identical to all passing rounds -> absmax 0 preserved.
// Epilogue straight-line (R18 lesson): packed uint2 sbuf stores + branch-free blkmin.
__global__ __launch_bounds__(256) void k_mfma(const ushort* __restrict__ zh,
                                              const ushort* __restrict__ eh,
                                              const float* __restrict__ bnorm,
                                              ushort* __restrict__ sbuf,
                                              float* __restrict__ rowblkmin) {
    __shared__ ushort Af[2][8 * 512];   // 2 x 8KB
    __shared__ ushort Bf[2][8 * 512];
    const int tid = threadIdx.x;
    const int lane = tid & 63;
    const int w = tid >> 6;
    const int wrow = (w >> 1) * 64, wcol = (w & 1) * 64;
    const int rbase = blockIdx.x * 128, cbase = blockIdx.y * 128;
    const int sr = tid >> 1, sh = tid & 1;            // staging: row 0..127, k-half 0..1
    const int g  = sr >> 4, r15 = sr & 15;            // staging chunk, row-in-chunk
    const int r16 = lane & 15, g4 = (lane >> 4) * 4;  // frag row/col, k-subgroup
    const int soff = g * 512 + r15 * 8 + sh * 4;      // LDS staging offset (ushorts)

    const ushort* ga = zh + (size_t)(rbase + sr) * DDIM + sh * 16;   // k=0 base
    const ushort* gb = eh + (size_t)(cbase + sr) * DDIM + sh * 16;

    f32x4 acc[4][4];
    #pragma unroll
    for (int i = 0; i < 4; ++i)
        #pragma unroll
        for (int j = 0; j < 4; ++j) acc[i][j] = (f32x4){0.f, 0.f, 0.f, 0.f};

    // prologue: stage tile 0 into buf 0; load tile 1 into held regs
    uint4 hA0, hA1, hB0, hB1;
    {
        const uint4 qa0 = *(const uint4*)ga;
        const uint4 qa1 = *(const uint4*)(ga + 8);
        const uint4 qb0 = *(const uint4*)gb;
        const uint4 qb1 = *(const uint4*)(gb + 8);
        ushort* pa = &Af[0][soff];
        *(uint2*)(pa +   0) = make_uint2(qa0.x, qa0.y);
        *(uint2*)(pa + 128) = make_uint2(qa0.z, qa0.w);
        *(uint2*)(pa + 256) = make_uint2(qa1.x, qa1.y);
        *(uint2*)(pa + 384) = make_uint2(qa1.z, qa1.w);
        ushort* pb = &Bf[0][soff];
        *(uint2*)(pb +   0) = make_uint2(qb0.x, qb0.y);
        *(uint2*)(pb + 128) = make_uint2(qb0.z, qb0.w);
        *(uint2*)(pb + 256) = make_uint2(qb1.x, qb1.y);
        *(uint2*)(pb + 384) = make_uint2(qb1.z, qb1.w);
        hA0 = *(const uint4*)(ga + 32);
        hA1 = *(const uint4*)(ga + 40);
        hB0 = *(const uint4*)(gb + 32);
        hB1 = *(const uint4*)(gb + 40);
    }
    __syncthreads();

    #pragma unroll
    for (int t = 0; t < 16; ++t) {      // tile t computed from buf[t&1]
        uint4 fA0, fA1, fB0, fB1;       // fresh: tile t+2
        if (t + 2 < 16) {               // ~1.5 iterations to land
            fA0 = *(const uint4*)(ga + (t + 2) * 32);
            fA1 = *(const uint4*)(ga + (t + 2) * 32 + 8);
            fB0 = *(const uint4*)(gb + (t + 2) * 32);
            fB1 = *(const uint4*)(gb + (t + 2) * 32 + 8);
        }
        bf16x8 af[4], bf[4];
        #pragma unroll
        for (int f = 0; f < 4; ++f) {
            af[f] = *(const bf16x8*)&Af[t & 1][((wrow >> 4) + f) * 512 + lane * 8];
            bf[f] = *(const bf16x8*)&Bf[t & 1][((wcol >> 4) + f) * 512 + lane * 8];
        }
        #pragma unroll
        for (int fi = 0; fi < 4; ++fi)
            #pragma unroll
            for (int fj = 0; fj < 4; ++fj)
                acc[fi][fj] = __builtin_amdgcn_mfma_f32_16x16x32_bf16(
                    af[fi], bf[fj], acc[fi][fj], 0, 0, 0);
        if (t + 1 < 16) {   // stage tile t+1 from held regs (loaded ~1.5 iters ago);
                            // safe: buf[(t+1)&1]'s readers finished before prev barrier
            ushort* pa = &Af[(t + 1) & 1][soff];
            *(uint2*)(pa +   0) = make_uint2(hA0.x, hA0.y);
            *(uint2*)(pa + 128) = make_uint2(hA0.z, hA0.w);
            *(uint2*)(pa + 256) = make_uint2(hA1.x, hA1.y);
            *(uint2*)(pa + 384) = make_uint2(hA1.z, hA1.w);
            ushort* pb = &Bf[(t + 1) & 1][soff];
            *(uint2*)(pb +   0) = make_uint2(hB0.x, hB0.y);
            *(uint2*)(pb + 128) = make_uint2(hB0.z, hB0.w);
            *(uint2*)(pb + 256) = make_uint2(hB1.x, hB1.y);
            *(uint2*)(pb + 384) = make_uint2(hB1.z, hB1.w);
            __syncthreads();
        }
        hA0 = fA0; hA1 = fA1; hB0 = fB0; hB1 = fB1;   // rotate (SSA, no copies)
    }

    // C/D layout: value (fi,fj,r) -> row = wrow+fi*16+g4+r, col = wcol+fj*16+r16
    float bn[4];
    #pragma unroll
    for (int fj = 0; fj < 4; ++fj) bn[fj] = bnorm[cbase + wcol + fj * 16 + r16];

    #pragma unroll
    for (int fi = 0; fi < 4; ++fi) {
        #pragma unroll
        for (int r = 0; r < 4; ++r) {
            const int row = rbase + wrow + fi * 16 + g4 + r;
            float s[4];
            #pragma unroll
            for (int fj = 0; fj < 4; ++fj) s[fj] = fmaf(-2.f, acc[fi][fj][r], bn[fj]);
            uint2* sp = (uint2*)(sbuf + (size_t)row * NE + cbase + wcol);
            sp[r16] = make_uint2(pack2(s[0], s[1]), pack2(s[2], s[3]));
            float m = fminf(fminf(s[0], s[1]), fminf(s[2], s[3]));
            #pragma unroll
            for (int x = 1; x < 16; x <<= 1) m = fminf(m, __shfl_xor(m, x));  // 16-lane grp
            if (r16 == 0)
                rowblkmin[(size_t)row * 64 + blockIdx.y * 2 + (w & 1)] = m;
        }
    }
}

// ---------------- exact numpy chain: sequential ascending-k FMA + exact bucketing ------
__device__ __forceinline__ unsigned long long exact_key(const float4* __restrict__ zp4,
                                                        const float* __restrict__ emb,
                                                        const float* __restrict__ bnorm,
                                                        float zn, int c) {
    const float4* ep4 = (const float4*)(emb + (size_t)c * DDIM);
    float acc = 0.f;
    #pragma unroll 8
    for (int q = 0; q < DDIM / 4; ++q) {
        const float4 zv = zp4[q];
        const float4 ev = ep4[q];
        acc = fmaf(zv.x, ev.x, acc);
        acc = fmaf(zv.y, ev.y, acc);
        acc = fmaf(zv.z, ev.z, acc);
        acc = fmaf(zv.w, ev.w, acc);
    }
    const float s = __fsub_rn(__fadd_rn(zn, bnorm[c]), __fmul_rn(2.f, acc));
    return ((unsigned long long)__float_as_uint(s) << 32) | (unsigned)c;
}

// ---------------- kernel 3: guided pick + exact resolve + gather + STE ----------------
// one wave per row; reads rowblkmin (4MB) + only flagged sbuf segments (~1.3 x 128B/row);
// candidates live only in per-wave LDS (no cross-block races); writes out.
// sbuf in-64-block permutation: col = b*64 + (i&3)*16 + (i>>2).
__global__ void k_pg(const ushort* __restrict__ sbuf, const float* __restrict__ rowblkmin,
                     const float* __restrict__ z, const float* __restrict__ emb,
                     const float* __restrict__ znorm, const float* __restrict__ bnorm,
                     float* __restrict__ out, unsigned* __restrict__ counts,
                     float* __restrict__ d2buf) {
    __shared__ int candL[4][MAXC];
    __shared__ unsigned cntL[4];
    const int lane = threadIdx.x & 63;
    const int w = threadIdx.x >> 6;
    const int row = blockIdx.x * 4 + w;
    if (threadIdx.x < 4) cntL[threadIdx.x] = 0u;
    __syncthreads();

    const float bm = rowblkmin[(size_t)row * 64 + lane];
    float gmin = bm;
    #pragma unroll
    for (int m = 32; m; m >>= 1) gmin = fminf(gmin, __shfl_xor(gmin, m));
    const float thr = gmin + MARGIN;
    unsigned long long bmask = __ballot(bm <= thr);   // expected ~1.3 blocks
    while (bmask) {
        const int b = __builtin_ctzll(bmask); bmask &= bmask - 1;
        const float val = __uint_as_float(
            (unsigned)sbuf[(size_t)row * NE + b * 64 + lane] << 16);
        if (val <= thr) {
            const unsigned slot = atomicAdd(&cntL[w], 1u);
            if (slot < MAXC)
                candL[w][slot] = b * 64 + (lane & 3) * 16 + (lane >> 2);
        }
    }
    __syncthreads();

    const int cnt = (int)cntL[w];
    int id;
    if (cnt == 1) {
        id = candL[w][0] & (NE - 1);
    } else {
        const float zn = znorm[row];
        const float4* zp4 = (const float4*)(z + (size_t)row * DDIM);
        unsigned long long best = ~0ULL;
        if (cnt >= 2 && cnt <= MAXC) {
            if (lane < cnt)
                best = exact_key(zp4, emb, bnorm, zn, candL[w][lane] & (NE - 1));
        } else {             // cnt==0 (impossible) or overflow: exact scan of all codes
            for (int c = lane; c < NE; c += 64) {
                const unsigned long long k = exact_key(zp4, emb, bnorm, zn, c);
                if (k < best) best = k;
            }
        }
        #pragma unroll
        for (int m = 32; m; m >>= 1) {
            const unsigned long long ov = __shfl_xor(best, m);
            if (ov < best) best = ov;
        }
        id = (int)(__shfl(best, 0) & (unsigned long long)(NE - 1));
    }

    const float* zp = z + (size_t)row * DDIM;
    const float* ep = emb + (size_t)id * DDIM;
    float* op = out + 1 + (size_t)row * DDIM;
    float d2 = 0.f;
    #pragma unroll
    for (int m = 0; m < 8; ++m) {
        const int k = m * 64 + lane;
        const float e = ep[k];
        const float zv = zp[k];
        const float t = e - zv;          // two-step rounding matches reference STE
        op[k] = zv + t;
        d2 = fmaf(t, t, d2);
    }
    #pragma unroll
    for (int m = 32; m; m >>= 1) d2 += __shfl_xor(d2, m);
    if (lane == 0) {
        atomicAdd(&counts[id], 1u);
        d2buf[row] = d2;
        out[1 + (size_t)NZ + row] = (float)id;
    }
}

// ---------------- kernel 4: finalize loss + perplexity ----------------
__global__ void k_final(const float* __restrict__ d2buf, const unsigned* __restrict__ counts,
                        float* __restrict__ out) {
    __shared__ double sh[256];
    __shared__ float  shf[256];
    const int tid = threadIdx.x;
    double ent = 0.0;
    for (int i = tid; i < NE; i += 256) {
        const double p = (double)counts[i] / (double)NROWS;
        ent += p * log(p + 1e-10);
    }
    float sse = 0.f;
    for (int i = tid; i < NROWS; i += 256) sse += d2buf[i];
    sh[tid] = ent; shf[tid] = sse;
    __syncthreads();
    for (int s = 128; s; s >>= 1) {
        if (tid < s) { sh[tid] += sh[tid + s]; shf[tid] += shf[tid + s]; }
        __syncthreads();
    }
    if (tid == 0) {
        out[0] = 1.25f * (shf[0] / (float)NZ);
        out[1 + (size_t)NZ + NROWS] = (float)exp(-sh[0]);
    }
}

extern "C" void kernel_launch(void* const* d_in, const int* in_sizes, int n_in,
                              void* d_out, int out_size, void* d_ws, size_t ws_size,
                              hipStream_t stream) {
    const float* z   = (const float*)d_in[0];
    const float* emb = (const float*)d_in[1];
    float* out = (float*)d_out;
    char* ws = (char*)d_ws;

    // zh/eh live inside out[1..NZ]: written by k_prep, read by k_mfma, and only
    // k_pg (strictly later in stream order) writes out -> no overlap anywhere.
    ushort* zh = (ushort*)(out + 4);                       // 16 MB
    ushort* eh = (ushort*)(out + 4 + 4194304);             //  4 MB

    size_t off = 0;
    float*    bnorm  = (float*)(ws + off); off += (size_t)NE * 4;          // 16KB
    unsigned* counts = (unsigned*)(ws + off); off += (size_t)NE * 4;       // 16KB
    float*    d2buf  = (float*)(ws + off); off += (size_t)NROWS * 4;       // 64KB
    float*    znorm  = (float*)(ws + off); off += (size_t)NROWS * 4;       // 64KB
    ushort*   sbuf   = (ushort*)(ws + off); off += (size_t)NROWS * NE * 2; // 128MB
    float*    rowblkmin = (float*)(ws + off); off += (size_t)NROWS * 64 * 4; // 4MB
    // total ~132.5MB == proven footprint

    k_prep<<<1280, 256, 0, stream>>>(z, emb, zh, eh, znorm, bnorm, counts);
    k_mfma<<<dim3(NROWS / 128, NE / 128), 256, 0, stream>>>(zh, eh, bnorm, sbuf, rowblkmin);
    k_pg<<<NROWS / 4, 256, 0, stream>>>(sbuf, rowblkmin, z, emb, znorm, bnorm, out, counts, d2buf);
    k_final<<<1, 256, 0, stream>>>(d2buf, counts, out);
}